// Round 11
// baseline (122.866 us; speedup 1.0000x reference)
//
#include <hip/hip_runtime.h>
#include <hip/hip_bf16.h>

typedef unsigned short u16;
typedef unsigned int u32;
typedef __attribute__((ext_vector_type(8))) short bf16x8;   // 8 bf16 (4 VGPRs)
typedef __attribute__((ext_vector_type(8))) u16 u16x8;
typedef __attribute__((ext_vector_type(4))) u16 u16x4;
typedef __attribute__((ext_vector_type(4))) u32 u32x4;
typedef __attribute__((ext_vector_type(4))) float f32x4;
typedef __attribute__((ext_vector_type(4))) _Float16 f16x4;
typedef __attribute__((ext_vector_type(8))) _Float16 f16x8;
typedef __attribute__((ext_vector_type(16))) float f32x16;

typedef const __attribute__((address_space(1))) void* gas1_t;
typedef __attribute__((address_space(3))) void* las3_t;

#define MFMA16(a,b,c) __builtin_amdgcn_mfma_f32_16x16x32_bf16((a),(b),(c),0,0,0)
#define MFMA32(a,b,c) __builtin_amdgcn_mfma_f32_32x32x16_bf16((a),(b),(c),0,0,0)

static constexpr int BB = 4, SS = 1024, DD = 1024, HH = 16;

static __device__ __forceinline__ u16 f2b(float x) {
  union { __hip_bfloat16 h; u16 u; } cv;
  cv.h = __float2bfloat16(x);
  return cv.u;
}
// packed f32x2 -> bf16x2 (RNE), src0 -> low16. PROVEN: round 3 passed with this asm.
static __device__ __forceinline__ u32 cvtpk(float lo, float hi) {
  u32 r;
  asm("v_cvt_pk_bf16_f32 %0, %1, %2" : "=v"(r) : "v"(lo), "v"(hi));
  return r;
}
static __device__ __forceinline__ float fmax3(float a, float b, float c) {
  return fmaxf(fmaxf(a, b), c);   // clang fuses to v_max3_f32
}

// ---------------- fused fp32 -> bf16 conversion (q,k,v + 4 weights) ----------------
__global__ __launch_bounds__(256) void cvt_all(
    const float* __restrict__ q, const float* __restrict__ k, const float* __restrict__ v,
    const float* __restrict__ wq_, const float* __restrict__ wk_, const float* __restrict__ wv_,
    const float* __restrict__ wp_,
    u16* __restrict__ qb, u16* __restrict__ kb, u16* __restrict__ vb,
    u16* __restrict__ wqb, u16* __restrict__ wkb, u16* __restrict__ wvb, u16* __restrict__ wpb) {
  int bid = blockIdx.x;
  const float* s; u16* d; int off;
  if      (bid < 4096)  { s = q;   d = qb;  off = bid; }
  else if (bid < 8192)  { s = k;   d = kb;  off = bid - 4096; }
  else if (bid < 12288) { s = v;   d = vb;  off = bid - 8192; }
  else if (bid < 13312) { s = wq_; d = wqb; off = bid - 12288; }
  else if (bid < 14336) { s = wk_; d = wkb; off = bid - 13312; }
  else if (bid < 15360) { s = wv_; d = wvb; off = bid - 14336; }
  else                  { s = wp_; d = wpb; off = bid - 15360; }
  int i = (off * 256 + threadIdx.x) * 4;
  float4 val = *(const float4*)(s + i);
  u16x4 r = { f2b(val.x), f2b(val.y), f2b(val.z), f2b(val.w) };
  *(u16x4*)(d + i) = r;
}

// ---------------- bias fp32 -> fp16 * log2(e), PRE-PERMUTED into MFMA fragment order -------
// Within each 64-k slice of row q: element k (kb,rq,hi,c) stored at ordered index
// idx = hi*32 + kb*16 + rq*4 + c, then 16B-granule XOR-swizzled by (q&7).
__global__ __launch_bounds__(256) void cvt_bias(const float* __restrict__ src,
                                                _Float16* __restrict__ dst) {
  const float L2E = 1.4426950408889634f;
  int i = (blockIdx.x * 256 + threadIdx.x) * 4;   // 4 consecutive k (c = 0..3)
  int row = i >> 10;                              // b*S + q
  int k = i & 1023;
  int kt = k >> 6, j = k & 63;
  int hi = (j >> 2) & 1, kb = j >> 5, rq = (j >> 3) & 3;
  int idx = hi * 32 + kb * 16 + rq * 4;           // c = 0
  int byte_in_slice = ((((idx >> 3) ^ (row & 7)) << 4) | ((idx & 7) << 1));
  float4 v = *(const float4*)(src + i);
  f16x4 r = { (_Float16)(v.x * L2E), (_Float16)(v.y * L2E),
              (_Float16)(v.z * L2E), (_Float16)(v.w * L2E) };
  char* p = (char*)dst + ((size_t)row * 1024 + kt * 64) * 2 + byte_in_slice;
  *(f16x4*)p = r;
}

// ---------------- GEMM: C[M,N] = A[M,K] * W[N,K]^T ----------------
// 128x128 tile, BK=64, T2 source-pre-swizzled LDS, XCD-chunked block swizzle.
template<typename OT, bool VTRANS>
__global__ __launch_bounds__(256) void gemm_bt(
    const u16* __restrict__ Abase, const u16* __restrict__ Wbase, OT* __restrict__ Cbase,
    u16* __restrict__ Tout, int N, int K, size_t sA, size_t sW, size_t sC) {
  const u16* A = Abase + (size_t)blockIdx.z * sA;
  const u16* W = Wbase + (size_t)blockIdx.z * sW;
  OT* C = Cbase + (size_t)blockIdx.z * sC;

  __shared__ __align__(16) u16 As[128 * 64];
  __shared__ __align__(16) u16 Bs[128 * 64];

  const int tid = threadIdx.x;
  const int lane = tid & 63;
  const int wid = tid >> 6;
  const int g = lane >> 4;
  const int li = lane & 15;

  const int hw = blockIdx.x + (blockIdx.y << 3);          // 0..255
  const int L = ((hw & 7) << 5) + (hw >> 3);
  const int brow = (L >> 3) * 128;
  const int bcol = (L & 7) * 128;

  const int wr = (wid >> 1) * 64;
  const int wc = (wid & 1) * 64;

  const int srow = wid * 8 + (lane >> 3);
  const int schunk = (lane & 7) ^ (lane >> 3);
  const u16* ga0 = A + (size_t)(brow + srow) * K + schunk * 8;
  const u16* gw0 = W + (size_t)(bcol + srow) * K + schunk * 8;

  f32x4 acc[4][4] = {};

  for (int k0 = 0; k0 < K; k0 += 64) {
#pragma unroll
    for (int i = 0; i < 4; ++i) {
      __builtin_amdgcn_global_load_lds((gas1_t)(const void*)(ga0 + (size_t)(i * 32) * K + k0),
                                       (las3_t)(void*)(As + (i * 32 + wid * 8) * 64), 16, 0, 0);
      __builtin_amdgcn_global_load_lds((gas1_t)(const void*)(gw0 + (size_t)(i * 32) * K + k0),
                                       (las3_t)(void*)(Bs + (i * 32 + wid * 8) * 64), 16, 0, 0);
    }
    __syncthreads();

#pragma unroll
    for (int kk = 0; kk < 2; ++kk) {
      bf16x8 a[4], b[4];
#pragma unroll
      for (int m = 0; m < 4; ++m) {
        int row = wr + m * 16 + li;
        a[m] = *(const bf16x8*)&As[row * 64 + (((kk * 4 + g) ^ (li & 7)) << 3)];
      }
#pragma unroll
      for (int n = 0; n < 4; ++n) {
        int row = wc + n * 16 + li;
        b[n] = *(const bf16x8*)&Bs[row * 64 + (((kk * 4 + g) ^ (li & 7)) << 3)];
      }
#pragma unroll
      for (int m = 0; m < 4; ++m)
#pragma unroll
        for (int n = 0; n < 4; ++n)
          acc[m][n] = MFMA16(a[m], b[n], acc[m][n]);
    }
    __syncthreads();
  }

  if (VTRANS && blockIdx.z == 2) {
#pragma unroll
    for (int m = 0; m < 4; ++m) {
#pragma unroll
      for (int n = 0; n < 4; ++n) {
        int c = bcol + wc + n * 16 + li;
        int h_ = c >> 6, dv = c & 63;
        int r0 = brow + wr + m * 16 + g * 4;
        int b_ = r0 >> 10, s0 = r0 & 1023;
        u16x4 val = { f2b(acc[m][n][0]), f2b(acc[m][n][1]),
                      f2b(acc[m][n][2]), f2b(acc[m][n][3]) };
        *(u16x4*)&Tout[(size_t)((b_ * HH + h_) * 64 + dv) * SS + s0] = val;
      }
    }
  } else {
#pragma unroll
    for (int m = 0; m < 4; ++m)
#pragma unroll
      for (int n = 0; n < 4; ++n)
#pragma unroll
        for (int j = 0; j < 4; ++j) {
          int r = brow + wr + m * 16 + g * 4 + j;
          int c = bcol + wc + n * 16 + li;
          if constexpr (sizeof(OT) == 2) C[(size_t)r * N + c] = (OT)f2b(acc[m][n][j]);
          else                           C[(size_t)r * N + c] = acc[m][n][j];
        }
  }
}

// ---------------- fused flash attention: all-gload_lds staging, exp2-domain softmax --------
// grid: (S/128, H, B) XCD-remapped; block 256 = 4 waves, each wave owns 32 q-rows (q = lane&31).
__global__ __launch_bounds__(256) void attn_kernel(
    const u16* __restrict__ Q, const u16* __restrict__ K, const u16* __restrict__ Vt,
    const _Float16* __restrict__ bias16, u16* __restrict__ O) {
  __shared__ __align__(16) u16 kbuf[2][64 * 64];   // [k][d], XOR-swizzled      (2x8 KB)
  __shared__ __align__(16) u16 vbuf[2][64 * 64];   // [dv][k], XOR-swizzled     (2x8 KB)
  __shared__ __align__(16) u16 bbuf[2][8192];      // fp16 bias*log2e, fragment-ordered

  const int tid = threadIdx.x;
  const int lane = tid & 63;
  const int wq = tid >> 6;
  const int hi = lane >> 5;
  const int ln = lane & 31;
  const u32 swz = (u32)(ln & 7) << 4;
  const float C1 = 1.4426950408889634f / 32.f;   // log2(e) * D^-0.5

  // bijective XCD-chunked remap: 512 blocks = 8 XCDs x 64
  const int flat = blockIdx.x + (blockIdx.y << 3) + (blockIdx.z << 7);
  const int L = ((flat & 7) << 6) | (flat >> 3);
  const int qt = L & 7, h = (L >> 3) & 15, b = L >> 7;
  const int q0 = qt * 128;
  const int qrow = q0 + wq * 32 + ln;       // this lane's softmax row

  // Q B-fragments: lane holds Q[qrow][d = dstep*16 + hi*8 + e]
  bf16x8 qf[4];
  {
    const u16* qp = Q + (size_t)(b * SS + qrow) * DD + h * 64 + hi * 8;
#pragma unroll
    for (int d = 0; d < 4; ++d) qf[d] = *(const bf16x8*)(qp + d * 16);
  }

  // K/V staging (gload_lds): instr j of wave wq covers rows wq*16 + j*8 + (lane>>3),
  // physical 16B piece lane&7 <- logical piece (lane&7)^(lane>>3) (source-pre-swizzle).
  const int srow = (lane >> 3);
  const int spc = ((lane & 7) ^ srow) * 8;          // source chunk (u16 elems)
  const u16* kgl = K + (size_t)(b * SS + wq * 16 + srow) * DD + h * 64 + spc;
  const u16* vgl = Vt + (size_t)((b * HH + h) * 64 + wq * 16 + srow) * SS + spc;

  // bias staging (gload_lds, linear thanks to cvt_bias pre-permute)
  const _Float16* bgl = bias16 + (size_t)(b * SS + q0 + wq * 32 + srow) * SS + (lane & 7) * 8;

  // bias read addresses: 4 x b128 per lane at qq*128 + ((hi*4+g)^(qq&7))*16
  const int qq = wq * 32 + ln;
  int baddr[4];
#pragma unroll
  for (int g = 0; g < 4; ++g)
    baddr[g] = qq * 128 + (((hi * 4 + g) ^ (ln & 7)) << 4);

  // ---- prologue: stage tile 0 ----
  {
    char* bd = (char*)bbuf[0] + wq * 4096;
#pragma unroll
    for (int i = 0; i < 4; ++i)
      __builtin_amdgcn_global_load_lds((gas1_t)(const void*)(bgl + (size_t)(i * 8) * SS),
                                       (las3_t)(void*)(bd + i * 1024), 16, 0, 0);
    char* kd = (char*)kbuf[0] + wq * 2048;
    char* vd = (char*)vbuf[0] + wq * 2048;
#pragma unroll
    for (int j = 0; j < 2; ++j) {
      __builtin_amdgcn_global_load_lds((gas1_t)(const void*)(kgl + (size_t)(j * 8) * DD),
                                       (las3_t)(void*)(kd + j * 1024), 16, 0, 0);
      __builtin_amdgcn_global_load_lds((gas1_t)(const void*)(vgl + (size_t)(j * 8) * SS),
                                       (las3_t)(void*)(vd + j * 1024), 16, 0, 0);
    }
  }
  __syncthreads();

  f32x16 o0 = {}, o1 = {};
  float m = -1e30f, lsum = 0.f;
  int cur = 0;

  for (int kt = 0; kt < 16; ++kt) {
    // 1. stage next tile (async, lands before the end-of-tile barrier of THIS tile)
    if (kt < 15) {
      char* bd = (char*)bbuf[cur ^ 1] + wq * 4096;
      const _Float16* bs = bgl + (kt + 1) * 64;
#pragma unroll
      for (int i = 0; i < 4; ++i)
        __builtin_amdgcn_global_load_lds((gas1_t)(const void*)(bs + (size_t)(i * 8) * SS),
                                         (las3_t)(void*)(bd + i * 1024), 16, 0, 0);
      char* kd = (char*)kbuf[cur ^ 1] + wq * 2048;
      char* vd = (char*)vbuf[cur ^ 1] + wq * 2048;
      const size_t k1 = (size_t)(kt + 1) * 64;
#pragma unroll
      for (int j = 0; j < 2; ++j) {
        __builtin_amdgcn_global_load_lds((gas1_t)(const void*)(kgl + (k1 + j * 8) * DD),
                                         (las3_t)(void*)(kd + j * 1024), 16, 0, 0);
        __builtin_amdgcn_global_load_lds((gas1_t)(const void*)(vgl + (size_t)(j * 8) * SS + k1),
                                         (las3_t)(void*)(vd + j * 1024), 16, 0, 0);
      }
    }

    // 2. swapped QK^T: s = mfma(K, Q) -> C: col = q = ln, row(k) = (r&3)+8*(r>>2)+4*hi (+32*kb)
    const char* kb_base = (const char*)kbuf[cur];
    f32x16 s[2];
#pragma unroll
    for (int kb = 0; kb < 2; ++kb) {
      f32x16 acc = {};
#pragma unroll
      for (int d = 0; d < 4; ++d) {
        bf16x8 kf = *(const bf16x8*)(kb_base + (kb * 32 + ln) * 128 + (((u32)(d * 32 + hi * 16)) ^ swz));
        acc = MFMA32(kf, qf[d], acc);
      }
      s[kb] = acc;
    }

    // 3. t = dot*log2e/32 + bias*log2e  (exp2 domain; 1 fma + 1 cvt per score)
    {
      const char* bbr = (const char*)bbuf[cur];
#pragma unroll
      for (int g = 0; g < 4; ++g) {
        f16x8 bv = *(const f16x8*)(bbr + baddr[g]);
        const int kb = g >> 1, rq0 = (g & 1) * 2;
#pragma unroll
        for (int e = 0; e < 8; ++e)
          s[kb][(rq0 + (e >> 2)) * 4 + (e & 3)] =
              fmaf(s[kb][(rq0 + (e >> 2)) * 4 + (e & 3)], C1, (float)bv[e]);
      }
    }

    // 4. row softmax in log2 domain: balanced max tree (depth ~5)
    float r8[8];
#pragma unroll
    for (int i = 0; i < 8; ++i)
      r8[i] = fmaxf(fmaxf(s[0][i], s[0][i + 8]), fmaxf(s[1][i], s[1][i + 8]));
    float mt = fmaxf(fmax3(r8[0], r8[1], r8[2]),
                     fmax3(fmax3(r8[3], r8[4], r8[5]), r8[6], r8[7]));
    mt = fmaxf(mt, __shfl_xor(mt, 32));

    bool resc = false;
    float fsc = 1.f;
    if (kt == 0) {
      m = mt;
    } else if (__any(mt > m + 11.5416f)) {   // T13 defer-max (8 * log2e)
      float mn = fmaxf(m, mt);
      fsc = exp2f(m - mn);
      m = mn;
      resc = true;
    }

    // p = exp2(t - m); pack via v_cvt_pk_bf16_f32; 4-way interleaved sum (chain depth 8)
    float rs0 = 0.f, rs1 = 0.f, rs2 = 0.f, rs3 = 0.f;
    u32 wv[2][8];
#pragma unroll
    for (int kb = 0; kb < 2; ++kb)
#pragma unroll
      for (int t = 0; t < 8; ++t) {
        float p0 = exp2f(s[kb][2 * t] - m);
        float p1 = exp2f(s[kb][2 * t + 1] - m);
        wv[kb][t] = cvtpk(p0, p1);
        if (t & 1) { rs2 += p0; rs3 += p1; }
        else       { rs0 += p0; rs1 += p1; }
      }
    float rs = (rs0 + rs1) + (rs2 + rs3);
    rs += __shfl_xor(rs, 32);
    lsum = lsum * fsc + rs;

    if (resc) {  // rescale O at q' = crow(j,hi), factor fetched via lane broadcast
#pragma unroll
      for (int j = 0; j < 16; ++j) {
        float fv = __shfl(fsc, (j & 3) + 8 * (j >> 2) + 4 * hi);
        o0[j] *= fv; o1[j] *= fv;
      }
    }

    // 5. PV: rebuild P A-fragments in-register (cross-hi shfl), then mfma(P, V)
    const char* vb_base = (const char*)vbuf[cur];
#pragma unroll
    for (int ks = 0; ks < 4; ++ks) {
      const int kb = ks >> 1, i0 = (ks & 1) * 4;
      u32 sA = hi ? wv[kb][i0 + 0] : wv[kb][i0 + 2];
      u32 sB = hi ? wv[kb][i0 + 1] : wv[kb][i0 + 3];
      u32 rA = (u32)__shfl_xor((int)sA, 32);
      u32 rB = (u32)__shfl_xor((int)sB, 32);
      u32 e0 = hi ? rA : wv[kb][i0 + 0];
      u32 e1 = hi ? rB : wv[kb][i0 + 1];
      u32 e2 = hi ? wv[kb][i0 + 2] : rA;
      u32 e3 = hi ? wv[kb][i0 + 3] : rB;
      union { u32x4 u; bf16x8 v; } pc;
      pc.u = (u32x4){e0, e1, e2, e3};
      bf16x8 pa = pc.v;
#pragma unroll
      for (int nv = 0; nv < 2; ++nv) {
        bf16x8 vf = *(const bf16x8*)(vb_base + (nv * 32 + ln) * 128 + (((u32)(ks * 32 + hi * 16)) ^ swz));
        if (nv == 0) o0 = MFMA32(pa, vf, o0);
        else         o1 = MFMA32(pa, vf, o1);
      }
    }

    // 6. single end-of-tile barrier (drains next-tile DMA after a full tile of cover)
    if (kt < 15) {
      __syncthreads();
      cur ^= 1;
    }
  }

  // epilogue: normalize (1/l broadcast via shfl) + write O (bf16)
  float inv = 1.0f / lsum;
#pragma unroll
  for (int j = 0; j < 16; ++j) {
    float iv = __shfl(inv, (j & 3) + 8 * (j >> 2) + 4 * hi);
    int q = q0 + wq * 32 + (j & 3) + 8 * (j >> 2) + 4 * hi;
    u16* op = O + (size_t)(b * SS + q) * DD + h * 64 + ln;
    op[0]  = f2b(o0[j] * iv);
    op[32] = f2b(o1[j] * iv);
  }
}

// ---------------- host launch ----------------
extern "C" void kernel_launch(void* const* d_in, const int* in_sizes, int n_in,
                              void* d_out, int out_size, void* d_ws, size_t ws_size,
                              hipStream_t stream) {
  const float* queries = (const float*)d_in[0];
  const float* keys    = (const float*)d_in[1];
  const float* values  = (const float*)d_in[2];
  const float* bias    = (const float*)d_in[3];
  const float* Wq      = (const float*)d_in[4];
  const float* Wk      = (const float*)d_in[5];
  const float* Wv      = (const float*)d_in[6];
  const float* Wp      = (const float*)d_in[7];
  float* out = (float*)d_out;

  char* ws = (char*)d_ws;
  const size_t MB = 1024 * 1024;
  u16* qb  = (u16*)(ws + 0 * MB);
  u16* kb  = (u16*)(ws + 8 * MB);
  u16* vb  = (u16*)(ws + 16 * MB);
  u16* wqb = (u16*)(ws + 24 * MB);
  u16* wkb = (u16*)(ws + 26 * MB);
  u16* wvb = (u16*)(ws + 28 * MB);
  u16* wpb = (u16*)(ws + 30 * MB);
  u16* Qb  = (u16*)(ws + 32 * MB);
  u16* Kb  = (u16*)(ws + 40 * MB);
  u16* Vtb = (u16*)(ws + 56 * MB);
  // bias16 (8.39 MB) overlays kb — dead after the QKV GEMM
  _Float16* bias16 = (_Float16*)(ws + 8 * MB);
  u16* Ob  = (u16*)(ws + 0 * MB);  // attn output over qb (dead after projections)

  const int nAct = BB * SS * DD;  // 4M
  const int nW = DD * DD;         // 1M

  cvt_all<<<dim3(16384), dim3(256), 0, stream>>>(
      queries, keys, values, Wq, Wk, Wv, Wp,
      qb, kb, vb, wqb, wkb, wvb, wpb);

  // QKV projections: z=0 -> Qb, z=1 -> Kb, z=2 -> Vt (transposed write)
  gemm_bt<u16, true><<<dim3(8, 32, 3), dim3(256), 0, stream>>>(
      qb, wqb, Qb, Vtb, DD, DD, (size_t)nAct, (size_t)nW, (size_t)nAct);

  // bias fp32 -> fp16*log2e, pre-permuted + pre-swizzled (kb region dead from here on)
  cvt_bias<<<dim3(4096), dim3(256), 0, stream>>>(bias, bias16);

  attn_kernel<<<dim3(8, 16, 4), dim3(256), 0, stream>>>(Qb, Kb, Vtb, bias16, Ob);

  gemm_bt<float, false><<<dim3(8, 32, 1), dim3(256), 0, stream>>>(
      Ob, wpb, out, nullptr, DD, DD, 0, 0, 0);
}

// Round 12
// 121.997 us; speedup vs baseline: 1.0071x; 1.0071x over previous
//
#include <hip/hip_runtime.h>
#include <hip/hip_bf16.h>

typedef unsigned short u16;
typedef unsigned int u32;
typedef __attribute__((ext_vector_type(8))) short bf16x8;   // 8 bf16 (4 VGPRs)
typedef __attribute__((ext_vector_type(8))) u16 u16x8;
typedef __attribute__((ext_vector_type(4))) u16 u16x4;
typedef __attribute__((ext_vector_type(4))) u32 u32x4;
typedef __attribute__((ext_vector_type(4))) float f32x4;
typedef __attribute__((ext_vector_type(4))) _Float16 f16x4;
typedef __attribute__((ext_vector_type(8))) _Float16 f16x8;
typedef __attribute__((ext_vector_type(16))) float f32x16;

typedef const __attribute__((address_space(1))) void* gas1_t;
typedef __attribute__((address_space(3))) void* las3_t;

#define MFMA16(a,b,c) __builtin_amdgcn_mfma_f32_16x16x32_bf16((a),(b),(c),0,0,0)
#define MFMA32(a,b,c) __builtin_amdgcn_mfma_f32_32x32x16_bf16((a),(b),(c),0,0,0)

static constexpr int BB = 4, SS = 1024, DD = 1024, HH = 16;

static __device__ __forceinline__ u16 f2b(float x) {
  union { __hip_bfloat16 h; u16 u; } cv;
  cv.h = __float2bfloat16(x);
  return cv.u;
}
static __device__ __forceinline__ u32 pk2(float a, float b) {
  return (u32)f2b(a) | ((u32)f2b(b) << 16);
}

// ---------------- fused fp32 -> bf16 conversion (q,k,v + 4 weights + bias pack) ----------------
// Blocks 16384.. handle the bias: fp32 -> fp16 packed in ATTN-CONSUMER order:
// tile (b,qt,kt) is 8192 fp16; value for consumer thread tid, fragment g, elem e at
// tile*8192 + g*2048 + tid*8 + e, where (from the verified C-layout k = kb*32+8rq+4hi+c):
// g = kb*2 + (rq>>1), e = (rq&1)*4 + c, tid = wq*64 + hi*32 + ln.
__global__ __launch_bounds__(256) void cvt_all(
    const float* __restrict__ q, const float* __restrict__ k, const float* __restrict__ v,
    const float* __restrict__ wq_, const float* __restrict__ wk_, const float* __restrict__ wv_,
    const float* __restrict__ wp_, const float* __restrict__ bias,
    u16* __restrict__ qb, u16* __restrict__ kb, u16* __restrict__ vb,
    u16* __restrict__ wqb, u16* __restrict__ wkb, u16* __restrict__ wvb, u16* __restrict__ wpb,
    _Float16* __restrict__ bias16) {
  int bid = blockIdx.x;
  if (bid >= 16384) {   // bias pack
    int i = ((bid - 16384) * 256 + threadIdx.x) * 4;   // 4 consecutive k (c = 0..3)
    int row = i >> 10;                                  // b*S + q
    int kk_ = i & 1023;
    int b_ = row >> 10, qq = row & 1023;
    int qt = qq >> 7, wq = (qq >> 5) & 3, ln = qq & 31;
    int kt = kk_ >> 6, kk = kk_ & 63;
    int kbf = kk >> 5, rem = kk & 31, rq = rem >> 3, inner = rem & 7;
    int hi = inner >> 2;                                // c spans 0..3
    int g = kbf * 2 + (rq >> 1);
    int ctid = wq * 64 + hi * 32 + ln;
    size_t tile = ((size_t)(b_ * 8 + qt) * 16 + kt) << 13;
    float4 val = *(const float4*)(bias + i);
    f16x4 r = { (_Float16)val.x, (_Float16)val.y, (_Float16)val.z, (_Float16)val.w };
    *(f16x4*)(bias16 + tile + g * 2048 + ctid * 8 + (rq & 1) * 4) = r;
    return;
  }
  const float* s; u16* d; int off;
  if      (bid < 4096)  { s = q;   d = qb;  off = bid; }
  else if (bid < 8192)  { s = k;   d = kb;  off = bid - 4096; }
  else if (bid < 12288) { s = v;   d = vb;  off = bid - 8192; }
  else if (bid < 13312) { s = wq_; d = wqb; off = bid - 12288; }
  else if (bid < 14336) { s = wk_; d = wkb; off = bid - 13312; }
  else if (bid < 15360) { s = wv_; d = wvb; off = bid - 14336; }
  else                  { s = wp_; d = wpb; off = bid - 15360; }
  int i = (off * 256 + threadIdx.x) * 4;
  float4 val = *(const float4*)(s + i);
  u16x4 r = { f2b(val.x), f2b(val.y), f2b(val.z), f2b(val.w) };
  *(u16x4*)(d + i) = r;
}

// ---------------- GEMM: C[M,N] = A[M,K] * W[N,K]^T ----------------
// 128x128 tile, BK=64, T2 source-pre-swizzled LDS, XCD-chunked block swizzle.
template<typename OT, bool VTRANS>
__global__ __launch_bounds__(256) void gemm_bt(
    const u16* __restrict__ Abase, const u16* __restrict__ Wbase, OT* __restrict__ Cbase,
    u16* __restrict__ Tout, int N, int K, size_t sA, size_t sW, size_t sC) {
  const u16* A = Abase + (size_t)blockIdx.z * sA;
  const u16* W = Wbase + (size_t)blockIdx.z * sW;
  OT* C = Cbase + (size_t)blockIdx.z * sC;

  __shared__ __align__(16) u16 As[128 * 64];
  __shared__ __align__(16) u16 Bs[128 * 64];

  const int tid = threadIdx.x;
  const int lane = tid & 63;
  const int wid = tid >> 6;
  const int g = lane >> 4;
  const int li = lane & 15;

  const int hw = blockIdx.x + (blockIdx.y << 3);          // 0..255
  const int L = ((hw & 7) << 5) + (hw >> 3);
  const int brow = (L >> 3) * 128;
  const int bcol = (L & 7) * 128;

  const int wr = (wid >> 1) * 64;
  const int wc = (wid & 1) * 64;

  const int srow = wid * 8 + (lane >> 3);
  const int schunk = (lane & 7) ^ (lane >> 3);
  const u16* ga0 = A + (size_t)(brow + srow) * K + schunk * 8;
  const u16* gw0 = W + (size_t)(bcol + srow) * K + schunk * 8;

  f32x4 acc[4][4] = {};

  for (int k0 = 0; k0 < K; k0 += 64) {
#pragma unroll
    for (int i = 0; i < 4; ++i) {
      __builtin_amdgcn_global_load_lds((gas1_t)(const void*)(ga0 + (size_t)(i * 32) * K + k0),
                                       (las3_t)(void*)(As + (i * 32 + wid * 8) * 64), 16, 0, 0);
      __builtin_amdgcn_global_load_lds((gas1_t)(const void*)(gw0 + (size_t)(i * 32) * K + k0),
                                       (las3_t)(void*)(Bs + (i * 32 + wid * 8) * 64), 16, 0, 0);
    }
    __syncthreads();

#pragma unroll
    for (int kk = 0; kk < 2; ++kk) {
      bf16x8 a[4], b[4];
#pragma unroll
      for (int m = 0; m < 4; ++m) {
        int row = wr + m * 16 + li;
        a[m] = *(const bf16x8*)&As[row * 64 + (((kk * 4 + g) ^ (li & 7)) << 3)];
      }
#pragma unroll
      for (int n = 0; n < 4; ++n) {
        int row = wc + n * 16 + li;
        b[n] = *(const bf16x8*)&Bs[row * 64 + (((kk * 4 + g) ^ (li & 7)) << 3)];
      }
#pragma unroll
      for (int m = 0; m < 4; ++m)
#pragma unroll
        for (int n = 0; n < 4; ++n)
          acc[m][n] = MFMA16(a[m], b[n], acc[m][n]);
    }
    __syncthreads();
  }

  if (VTRANS && blockIdx.z == 2) {
#pragma unroll
    for (int m = 0; m < 4; ++m) {
#pragma unroll
      for (int n = 0; n < 4; ++n) {
        int c = bcol + wc + n * 16 + li;
        int h_ = c >> 6, dv = c & 63;
        int r0 = brow + wr + m * 16 + g * 4;
        int b_ = r0 >> 10, s0 = r0 & 1023;
        u16x4 val = { f2b(acc[m][n][0]), f2b(acc[m][n][1]),
                      f2b(acc[m][n][2]), f2b(acc[m][n][3]) };
        *(u16x4*)&Tout[(size_t)((b_ * HH + h_) * 64 + dv) * SS + s0] = val;
      }
    }
  } else {
#pragma unroll
    for (int m = 0; m < 4; ++m)
#pragma unroll
      for (int n = 0; n < 4; ++n)
#pragma unroll
        for (int j = 0; j < 4; ++j) {
          int r = brow + wr + m * 16 + g * 4 + j;
          int c = bcol + wc + n * 16 + li;
          if constexpr (sizeof(OT) == 2) C[(size_t)r * N + c] = (OT)f2b(acc[m][n][j]);
          else                           C[(size_t)r * N + c] = acc[m][n][j];
        }
  }
}

// ---------------- fused flash attention: r10 body + bias in registers (zero bias LDS) ------
// grid: (S/128, H, B) XCD-remapped; block 256 = 4 waves, each wave owns 32 q-rows (q = lane&31).
__global__ __launch_bounds__(256) void attn_kernel(
    const u16* __restrict__ Q, const u16* __restrict__ K, const u16* __restrict__ Vt,
    const _Float16* __restrict__ bias16, u16* __restrict__ O) {
  __shared__ __align__(16) u16 kbuf[2][64 * 64];   // [k][d], XOR-swizzled      (2x8 KB)
  __shared__ __align__(16) u16 vbuf[2][64 * 64];   // [dv][k], XOR-swizzled     (2x8 KB)

  const int tid = threadIdx.x;
  const int lane = tid & 63;
  const int wq = tid >> 6;
  const int hi = lane >> 5;
  const int ln = lane & 31;
  const u32 swz = (u32)(ln & 7) << 4;

  // bijective XCD-chunked remap: 512 blocks = 8 XCDs x 64
  const int flat = blockIdx.x + (blockIdx.y << 3) + (blockIdx.z << 7);
  const int L = ((flat & 7) << 6) | (flat >> 3);
  const int qt = L & 7, h = (L >> 3) & 15, b = L >> 7;
  const int q0 = qt * 128;
  const int qrow = q0 + wq * 32 + ln;       // this lane's softmax row

  // Q B-fragments: lane holds Q[qrow][d = dstep*16 + hi*8 + e]
  bf16x8 qf[4];
  {
    const u16* qp = Q + (size_t)(b * SS + qrow) * DD + h * 64 + hi * 8;
#pragma unroll
    for (int d = 0; d < 4; ++d) qf[d] = *(const bf16x8*)(qp + d * 16);
  }

  // K/V staging (gload_lds): instr j of wave wq covers rows wq*16 + j*8 + (lane>>3),
  // physical 16B piece lane&7 <- logical piece (lane&7)^(lane>>3) (source-pre-swizzle).
  const int srow = (lane >> 3);
  const int spc = ((lane & 7) ^ srow) * 8;          // source chunk (u16 elems)
  const u16* kgl = K + (size_t)(b * SS + wq * 16 + srow) * DD + h * 64 + spc;
  const u16* vgl = Vt + (size_t)((b * HH + h) * 64 + wq * 16 + srow) * SS + spc;

  // bias: consumer-ordered tiles; per tile 4 coalesced 16B loads/thread into regs
  const _Float16* btile = bias16 + (((size_t)(b * 8 + qt) * 16) << 13) + tid * 8;

  // ---- prologue: stage tile 0 (K/V via gload_lds, bias via regs) ----
  {
    char* kd = (char*)kbuf[0] + wq * 2048;
    char* vd = (char*)vbuf[0] + wq * 2048;
#pragma unroll
    for (int j = 0; j < 2; ++j) {
      __builtin_amdgcn_global_load_lds((gas1_t)(const void*)(kgl + (size_t)(j * 8) * DD),
                                       (las3_t)(void*)(kd + j * 1024), 16, 0, 0);
      __builtin_amdgcn_global_load_lds((gas1_t)(const void*)(vgl + (size_t)(j * 8) * SS),
                                       (las3_t)(void*)(vd + j * 1024), 16, 0, 0);
    }
  }
  f16x8 bbr[4], bbn[4];
#pragma unroll
  for (int g = 0; g < 4; ++g)
    bbr[g] = *(const f16x8*)(btile + g * 2048);
  __syncthreads();

  f32x16 o0 = {}, o1 = {};
  float m = -1e30f, lsum = 0.f;
  int cur = 0;

  for (int kt = 0; kt < 16; ++kt) {
    // 1. stage next tile: K/V -> LDS (async), bias -> regs
    if (kt < 15) {
      char* kd = (char*)kbuf[cur ^ 1] + wq * 2048;
      char* vd = (char*)vbuf[cur ^ 1] + wq * 2048;
      const size_t k1 = (size_t)(kt + 1) * 64;
#pragma unroll
      for (int j = 0; j < 2; ++j) {
        __builtin_amdgcn_global_load_lds((gas1_t)(const void*)(kgl + (k1 + j * 8) * DD),
                                         (las3_t)(void*)(kd + j * 1024), 16, 0, 0);
        __builtin_amdgcn_global_load_lds((gas1_t)(const void*)(vgl + (size_t)(j * 8) * SS + k1),
                                         (las3_t)(void*)(vd + j * 1024), 16, 0, 0);
      }
      const _Float16* bt = btile + ((size_t)(kt + 1) << 13);
#pragma unroll
      for (int g = 0; g < 4; ++g)
        bbn[g] = *(const f16x8*)(bt + g * 2048);
    }

    // 2. swapped QK^T: s = mfma(K, Q) -> C: col = q = ln, row(k) = (r&3)+8*(r>>2)+4*hi (+32*kb)
    const char* kb_base = (const char*)kbuf[cur];
    f32x16 s[2];
#pragma unroll
    for (int kb = 0; kb < 2; ++kb) {
      f32x16 acc = {};
#pragma unroll
      for (int d = 0; d < 4; ++d) {
        bf16x8 kf = *(const bf16x8*)(kb_base + (kb * 32 + ln) * 128 + (((u32)(d * 32 + hi * 16)) ^ swz));
        acc = MFMA32(kf, qf[d], acc);
      }
      s[kb] = acc;
    }

    // 3. scale (D^-0.5 = 1/32) + bias from regs (fragment-ordered fp16)
#pragma unroll
    for (int g = 0; g < 4; ++g) {
      const int kb = g >> 1, rq0 = (g & 1) * 2;
#pragma unroll
      for (int e = 0; e < 8; ++e)
        s[kb][(rq0 + (e >> 2)) * 4 + (e & 3)] =
            fmaf(s[kb][(rq0 + (e >> 2)) * 4 + (e & 3)], 0.03125f, (float)bbr[g][e]);
    }

    // 4. in-register row softmax (row is lane-local; only cross-hi shuffle needed)
    float mt = -1e30f;
#pragma unroll
    for (int r = 0; r < 16; ++r) { mt = fmaxf(mt, s[0][r]); mt = fmaxf(mt, s[1][r]); }
    mt = fmaxf(mt, __shfl_xor(mt, 32));

    bool resc = false;
    float fsc = 1.f;
    if (kt == 0) {
      m = mt;
    } else if (__any(mt > m + 8.f)) {   // T13 defer-max
      float mn = fmaxf(m, mt);
      fsc = __expf(m - mn);
      m = mn;
      resc = true;
    }

    float rs = 0.f;
    u32 wv[2][8];
#pragma unroll
    for (int kb = 0; kb < 2; ++kb)
#pragma unroll
      for (int t = 0; t < 8; ++t) {
        float p0 = __expf(s[kb][2 * t] - m);
        float p1 = __expf(s[kb][2 * t + 1] - m);
        rs += p0 + p1;
        wv[kb][t] = pk2(p0, p1);
      }
    rs += __shfl_xor(rs, 32);
    lsum = lsum * fsc + rs;

    if (resc) {  // rescale O at q' = crow(j,hi), factor fetched via lane broadcast
#pragma unroll
      for (int j = 0; j < 16; ++j) {
        float fv = __shfl(fsc, (j & 3) + 8 * (j >> 2) + 4 * hi);
        o0[j] *= fv; o1[j] *= fv;
      }
    }

    // 5. PV: rebuild P A-fragments in-register (cross-hi shfl), then mfma(P, V)
    const char* vb_base = (const char*)vbuf[cur];
#pragma unroll
    for (int ks = 0; ks < 4; ++ks) {
      const int kb = ks >> 1, i0 = (ks & 1) * 4;
      u32 sA = hi ? wv[kb][i0 + 0] : wv[kb][i0 + 2];
      u32 sB = hi ? wv[kb][i0 + 1] : wv[kb][i0 + 3];
      u32 rA = (u32)__shfl_xor((int)sA, 32);
      u32 rB = (u32)__shfl_xor((int)sB, 32);
      u32 e0 = hi ? rA : wv[kb][i0 + 0];
      u32 e1 = hi ? rB : wv[kb][i0 + 1];
      u32 e2 = hi ? wv[kb][i0 + 2] : rA;
      u32 e3 = hi ? wv[kb][i0 + 3] : rB;
      union { u32x4 u; bf16x8 v; } pc;
      pc.u = (u32x4){e0, e1, e2, e3};
      bf16x8 pa = pc.v;
#pragma unroll
      for (int nv = 0; nv < 2; ++nv) {
        bf16x8 vf = *(const bf16x8*)(vb_base + (nv * 32 + ln) * 128 + (((u32)(ks * 32 + hi * 16)) ^ swz));
        if (nv == 0) o0 = MFMA32(pa, vf, o0);
        else         o1 = MFMA32(pa, vf, o1);
      }
    }

    // 6. single end-of-tile barrier; rotate buffers
    if (kt < 15) {
      __syncthreads();
      cur ^= 1;
#pragma unroll
      for (int g = 0; g < 4; ++g) bbr[g] = bbn[g];
    }
  }

  // epilogue: normalize (1/l broadcast via shfl) + write O (bf16)
  float inv = 1.0f / lsum;
#pragma unroll
  for (int j = 0; j < 16; ++j) {
    float iv = __shfl(inv, (j & 3) + 8 * (j >> 2) + 4 * hi);
    int q = q0 + wq * 32 + (j & 3) + 8 * (j >> 2) + 4 * hi;
    u16* op = O + (size_t)(b * SS + q) * DD + h * 64 + ln;
    op[0]  = f2b(o0[j] * iv);
    op[32] = f2b(o1[j] * iv);
  }
}

// ---------------- host launch ----------------
extern "C" void kernel_launch(void* const* d_in, const int* in_sizes, int n_in,
                              void* d_out, int out_size, void* d_ws, size_t ws_size,
                              hipStream_t stream) {
  const float* queries = (const float*)d_in[0];
  const float* keys    = (const float*)d_in[1];
  const float* values  = (const float*)d_in[2];
  const float* bias    = (const float*)d_in[3];
  const float* Wq      = (const float*)d_in[4];
  const float* Wk      = (const float*)d_in[5];
  const float* Wv      = (const float*)d_in[6];
  const float* Wp      = (const float*)d_in[7];
  float* out = (float*)d_out;

  char* ws = (char*)d_ws;
  const size_t MB = 1024 * 1024;
  u16* qb  = (u16*)(ws + 0 * MB);
  u16* kb  = (u16*)(ws + 8 * MB);
  u16* vb  = (u16*)(ws + 16 * MB);
  u16* wqb = (u16*)(ws + 24 * MB);
  u16* wkb = (u16*)(ws + 26 * MB);
  u16* wvb = (u16*)(ws + 28 * MB);
  u16* wpb = (u16*)(ws + 30 * MB);
  u16* Qb  = (u16*)(ws + 32 * MB);
  u16* Kb  = (u16*)(ws + 40 * MB);
  _Float16* bias16 = (_Float16*)(ws + 48 * MB);  // free region (old Vb, unused since r8)
  u16* Vtb = (u16*)(ws + 56 * MB);
  u16* Ob  = (u16*)(ws + 0 * MB);  // attn output over qb (dead after projections)

  const int nAct = BB * SS * DD;  // 4M
  const int nW = DD * DD;         // 1M

  // all conversions + bias pack in ONE launch (bias16 no longer overlays live data)
  cvt_all<<<dim3(20480), dim3(256), 0, stream>>>(
      queries, keys, values, Wq, Wk, Wv, Wp, bias,
      qb, kb, vb, wqb, wkb, wvb, wpb, bias16);

  // QKV projections: z=0 -> Qb, z=1 -> Kb, z=2 -> Vt (transposed write)
  gemm_bt<u16, true><<<dim3(8, 32, 3), dim3(256), 0, stream>>>(
      qb, wqb, Qb, Vtb, DD, DD, (size_t)nAct, (size_t)nW, (size_t)nAct);

  attn_kernel<<<dim3(8, 16, 4), dim3(256), 0, stream>>>(Qb, Kb, Vtb, bias16, Ob);

  gemm_bt<float, false><<<dim3(8, 32, 1), dim3(256), 0, stream>>>(
      Ob, wpb, out, nullptr, DD, DD, 0, 0, 0);
}

// Round 13
// 117.426 us; speedup vs baseline: 1.0463x; 1.0389x over previous
//
#include <hip/hip_runtime.h>
#include <hip/hip_bf16.h>

typedef unsigned short u16;
typedef unsigned int u32;
typedef __attribute__((ext_vector_type(8))) short bf16x8;   // 8 bf16 (4 VGPRs)
typedef __attribute__((ext_vector_type(8))) u16 u16x8;
typedef __attribute__((ext_vector_type(4))) u16 u16x4;
typedef __attribute__((ext_vector_type(4))) u32 u32x4;
typedef __attribute__((ext_vector_type(4))) float f32x4;
typedef __attribute__((ext_vector_type(4))) _Float16 f16x4;
typedef __attribute__((ext_vector_type(8))) _Float16 f16x8;
typedef __attribute__((ext_vector_type(16))) float f32x16;

typedef const __attribute__((address_space(1))) void* gas1_t;
typedef __attribute__((address_space(3))) void* las3_t;

#define MFMA16(a,b,c) __builtin_amdgcn_mfma_f32_16x16x32_bf16((a),(b),(c),0,0,0)
#define MFMA32(a,b,c) __builtin_amdgcn_mfma_f32_32x32x16_bf16((a),(b),(c),0,0,0)

static constexpr int BB = 4, SS = 1024, DD = 1024, HH = 16;

static __device__ __forceinline__ u16 f2b(float x) {
  union { __hip_bfloat16 h; u16 u; } cv;
  cv.h = __float2bfloat16(x);
  return cv.u;
}
static __device__ __forceinline__ u32 pk2(float a, float b) {
  return (u32)f2b(a) | ((u32)f2b(b) << 16);
}

// ---------------- fused fp32 -> bf16 conversion (q,k,v + 4 weights + bias pack) ----------------
// Bias pack (blocks 16384..18431): ONE THREAD PER 16B OUTPUT GRANULE -> perfectly
// coalesced writes. Granule (tile T, frag g, consumer-thread ctid) holds e=0..7:
//   e<4:  bias[row][k0 + e]        k0 = kt*64 + kb*32 + j*16 + hi*4
//   e>=4: bias[row][k0 + 8 + e-4]
// with kb = g>>1, j = g&1, ctid = wq*64 + hi*32 + ln, row = qt*128 + wq*32 + ln.
// (Element-equivalent to the verified r12 layout: e = (rq&1)*4 + c, rq = 2j + (e>>2).)
__global__ __launch_bounds__(256) void cvt_all(
    const float* __restrict__ q, const float* __restrict__ k, const float* __restrict__ v,
    const float* __restrict__ wq_, const float* __restrict__ wk_, const float* __restrict__ wv_,
    const float* __restrict__ wp_, const float* __restrict__ bias,
    u16* __restrict__ qb, u16* __restrict__ kb, u16* __restrict__ vb,
    u16* __restrict__ wqb, u16* __restrict__ wkb, u16* __restrict__ wvb, u16* __restrict__ wpb,
    _Float16* __restrict__ bias16) {
  int bid = blockIdx.x;
  if (bid >= 16384) {   // bias pack, granule-per-thread
    int G = (bid - 16384) * 256 + threadIdx.x;       // granule id, 524288 total
    int gi = G & 1023;
    int ctid = gi & 255, g = gi >> 8;
    int T = G >> 10;                                  // (b*8 + qt)*16 + kt
    int kt = T & 15, qt = (T >> 4) & 7, b_ = T >> 7;
    int wq = ctid >> 6, hi = (ctid >> 5) & 1, ln = ctid & 31;
    int qrow = qt * 128 + wq * 32 + ln;
    int kbf = g >> 1, j = g & 1;
    int k0 = kt * 64 + kbf * 32 + j * 16 + hi * 4;
    const float* src = bias + (((size_t)(b_ * 1024 + qrow)) << 10) + k0;
    float4 lo = *(const float4*)(src);
    float4 up = *(const float4*)(src + 8);
    f16x8 r = { (_Float16)lo.x, (_Float16)lo.y, (_Float16)lo.z, (_Float16)lo.w,
                (_Float16)up.x, (_Float16)up.y, (_Float16)up.z, (_Float16)up.w };
    *(f16x8*)(bias16 + (((size_t)T) << 13) + g * 2048 + ctid * 8) = r;
    return;
  }
  const float* s; u16* d; int off;
  if      (bid < 4096)  { s = q;   d = qb;  off = bid; }
  else if (bid < 8192)  { s = k;   d = kb;  off = bid - 4096; }
  else if (bid < 12288) { s = v;   d = vb;  off = bid - 8192; }
  else if (bid < 13312) { s = wq_; d = wqb; off = bid - 12288; }
  else if (bid < 14336) { s = wk_; d = wkb; off = bid - 13312; }
  else if (bid < 15360) { s = wv_; d = wvb; off = bid - 14336; }
  else                  { s = wp_; d = wpb; off = bid - 15360; }
  int i = (off * 256 + threadIdx.x) * 4;
  float4 val = *(const float4*)(s + i);
  u16x4 r = { f2b(val.x), f2b(val.y), f2b(val.z), f2b(val.w) };
  *(u16x4*)(d + i) = r;
}

// ---------------- GEMM: C[M,N] = A[M,K] * W[N,K]^T  (QKV; 256 thr, 4 waves) ----------------
// 128x128 tile, BK=64, T2 source-pre-swizzled LDS, XCD-chunked block swizzle.
template<typename OT, bool VTRANS>
__global__ __launch_bounds__(256) void gemm_bt(
    const u16* __restrict__ Abase, const u16* __restrict__ Wbase, OT* __restrict__ Cbase,
    u16* __restrict__ Tout, int N, int K, size_t sA, size_t sW, size_t sC) {
  const u16* A = Abase + (size_t)blockIdx.z * sA;
  const u16* W = Wbase + (size_t)blockIdx.z * sW;
  OT* C = Cbase + (size_t)blockIdx.z * sC;

  __shared__ __align__(16) u16 As[128 * 64];
  __shared__ __align__(16) u16 Bs[128 * 64];

  const int tid = threadIdx.x;
  const int lane = tid & 63;
  const int wid = tid >> 6;
  const int g = lane >> 4;
  const int li = lane & 15;

  const int hw = blockIdx.x + (blockIdx.y << 3);          // 0..255
  const int L = ((hw & 7) << 5) + (hw >> 3);
  const int brow = (L >> 3) * 128;
  const int bcol = (L & 7) * 128;

  const int wr = (wid >> 1) * 64;
  const int wc = (wid & 1) * 64;

  const int srow = wid * 8 + (lane >> 3);
  const int schunk = (lane & 7) ^ (lane >> 3);
  const u16* ga0 = A + (size_t)(brow + srow) * K + schunk * 8;
  const u16* gw0 = W + (size_t)(bcol + srow) * K + schunk * 8;

  f32x4 acc[4][4] = {};

  for (int k0 = 0; k0 < K; k0 += 64) {
#pragma unroll
    for (int i = 0; i < 4; ++i) {
      __builtin_amdgcn_global_load_lds((gas1_t)(const void*)(ga0 + (size_t)(i * 32) * K + k0),
                                       (las3_t)(void*)(As + (i * 32 + wid * 8) * 64), 16, 0, 0);
      __builtin_amdgcn_global_load_lds((gas1_t)(const void*)(gw0 + (size_t)(i * 32) * K + k0),
                                       (las3_t)(void*)(Bs + (i * 32 + wid * 8) * 64), 16, 0, 0);
    }
    __syncthreads();

#pragma unroll
    for (int kk = 0; kk < 2; ++kk) {
      bf16x8 a[4], b[4];
#pragma unroll
      for (int m = 0; m < 4; ++m) {
        int row = wr + m * 16 + li;
        a[m] = *(const bf16x8*)&As[row * 64 + (((kk * 4 + g) ^ (li & 7)) << 3)];
      }
#pragma unroll
      for (int n = 0; n < 4; ++n) {
        int row = wc + n * 16 + li;
        b[n] = *(const bf16x8*)&Bs[row * 64 + (((kk * 4 + g) ^ (li & 7)) << 3)];
      }
#pragma unroll
      for (int m = 0; m < 4; ++m)
#pragma unroll
        for (int n = 0; n < 4; ++n)
          acc[m][n] = MFMA16(a[m], b[n], acc[m][n]);
    }
    __syncthreads();
  }

  if (VTRANS && blockIdx.z == 2) {
#pragma unroll
    for (int m = 0; m < 4; ++m) {
#pragma unroll
      for (int n = 0; n < 4; ++n) {
        int c = bcol + wc + n * 16 + li;
        int h_ = c >> 6, dv = c & 63;
        int r0 = brow + wr + m * 16 + g * 4;
        int b_ = r0 >> 10, s0 = r0 & 1023;
        u16x4 val = { f2b(acc[m][n][0]), f2b(acc[m][n][1]),
                      f2b(acc[m][n][2]), f2b(acc[m][n][3]) };
        *(u16x4*)&Tout[(size_t)((b_ * HH + h_) * 64 + dv) * SS + s0] = val;
      }
    }
  } else {
#pragma unroll
    for (int m = 0; m < 4; ++m)
#pragma unroll
      for (int n = 0; n < 4; ++n)
#pragma unroll
        for (int j = 0; j < 4; ++j) {
          int r = brow + wr + m * 16 + g * 4 + j;
          int c = bcol + wc + n * 16 + li;
          if constexpr (sizeof(OT) == 2) C[(size_t)r * N + c] = (OT)f2b(acc[m][n][j]);
          else                           C[(size_t)r * N + c] = acc[m][n][j];
        }
  }
}

// ---------------- proj GEMM: 512 threads / 8 waves (2 waves/SIMD vs 1) ----------------
// Same 128x128 tile & swizzles; waves 4x2, each 32x64 output (acc[2][4]).
__global__ __launch_bounds__(512) void gemm_proj(
    const u16* __restrict__ A, const u16* __restrict__ W, float* __restrict__ C,
    int N, int K) {
  __shared__ __align__(16) u16 As[128 * 64];
  __shared__ __align__(16) u16 Bs[128 * 64];

  const int tid = threadIdx.x;
  const int lane = tid & 63;
  const int wid = tid >> 6;                 // 0..7
  const int g = lane >> 4;
  const int li = lane & 15;

  const int hw = blockIdx.x + (blockIdx.y << 3);          // 0..255
  const int L = ((hw & 7) << 5) + (hw >> 3);
  const int brow = (L >> 3) * 128;
  const int bcol = (L & 7) * 128;

  const int wr = (wid >> 1) * 32;           // 4 row-strips of 32
  const int wc = (wid & 1) * 64;            // 2 col-strips of 64

  // staging: 512 thr x 16B = 64 rows per issue; srow = tid>>3 (0..63), piece = tid&7
  const int srow = tid >> 3;
  const int schunk = (tid & 7) ^ (srow & 7);
  const u16* ga0 = A + (size_t)(brow + srow) * K + schunk * 8;
  const u16* gw0 = W + (size_t)(bcol + srow) * K + schunk * 8;

  f32x4 acc[2][4] = {};

  for (int k0 = 0; k0 < K; k0 += 64) {
#pragma unroll
    for (int i = 0; i < 2; ++i) {
      __builtin_amdgcn_global_load_lds((gas1_t)(const void*)(ga0 + (size_t)(i * 64) * K + k0),
                                       (las3_t)(void*)(As + (i * 64 + (wid << 3)) * 64), 16, 0, 0);
      __builtin_amdgcn_global_load_lds((gas1_t)(const void*)(gw0 + (size_t)(i * 64) * K + k0),
                                       (las3_t)(void*)(Bs + (i * 64 + (wid << 3)) * 64), 16, 0, 0);
    }
    __syncthreads();

#pragma unroll
    for (int kk = 0; kk < 2; ++kk) {
      bf16x8 a[2], b[4];
#pragma unroll
      for (int m = 0; m < 2; ++m) {
        int row = wr + m * 16 + li;
        a[m] = *(const bf16x8*)&As[row * 64 + (((kk * 4 + g) ^ (li & 7)) << 3)];
      }
#pragma unroll
      for (int n = 0; n < 4; ++n) {
        int row = wc + n * 16 + li;
        b[n] = *(const bf16x8*)&Bs[row * 64 + (((kk * 4 + g) ^ (li & 7)) << 3)];
      }
#pragma unroll
      for (int m = 0; m < 2; ++m)
#pragma unroll
        for (int n = 0; n < 4; ++n)
          acc[m][n] = MFMA16(a[m], b[n], acc[m][n]);
    }
    __syncthreads();
  }

#pragma unroll
  for (int m = 0; m < 2; ++m)
#pragma unroll
    for (int n = 0; n < 4; ++n)
#pragma unroll
      for (int j = 0; j < 4; ++j) {
        int r = brow + wr + m * 16 + g * 4 + j;
        int c = bcol + wc + n * 16 + li;
        C[(size_t)r * N + c] = acc[m][n][j];
      }
}

// ---------------- fused flash attention (r10/r12 body, UNCHANGED) ----------------
// grid: (S/128, H, B) XCD-remapped; block 256 = 4 waves, each wave owns 32 q-rows (q = lane&31).
__global__ __launch_bounds__(256) void attn_kernel(
    const u16* __restrict__ Q, const u16* __restrict__ K, const u16* __restrict__ Vt,
    const _Float16* __restrict__ bias16, u16* __restrict__ O) {
  __shared__ __align__(16) u16 kbuf[2][64 * 64];   // [k][d], XOR-swizzled      (2x8 KB)
  __shared__ __align__(16) u16 vbuf[2][64 * 64];   // [dv][k], XOR-swizzled     (2x8 KB)

  const int tid = threadIdx.x;
  const int lane = tid & 63;
  const int wq = tid >> 6;
  const int hi = lane >> 5;
  const int ln = lane & 31;
  const u32 swz = (u32)(ln & 7) << 4;

  // bijective XCD-chunked remap: 512 blocks = 8 XCDs x 64
  const int flat = blockIdx.x + (blockIdx.y << 3) + (blockIdx.z << 7);
  const int L = ((flat & 7) << 6) | (flat >> 3);
  const int qt = L & 7, h = (L >> 3) & 15, b = L >> 7;
  const int q0 = qt * 128;
  const int qrow = q0 + wq * 32 + ln;       // this lane's softmax row

  // Q B-fragments: lane holds Q[qrow][d = dstep*16 + hi*8 + e]
  bf16x8 qf[4];
  {
    const u16* qp = Q + (size_t)(b * SS + qrow) * DD + h * 64 + hi * 8;
#pragma unroll
    for (int d = 0; d < 4; ++d) qf[d] = *(const bf16x8*)(qp + d * 16);
  }

  // K/V staging (gload_lds): instr j of wave wq covers rows wq*16 + j*8 + (lane>>3),
  // physical 16B piece lane&7 <- logical piece (lane&7)^(lane>>3) (source-pre-swizzle).
  const int srow = (lane >> 3);
  const int spc = ((lane & 7) ^ srow) * 8;          // source chunk (u16 elems)
  const u16* kgl = K + (size_t)(b * SS + wq * 16 + srow) * DD + h * 64 + spc;
  const u16* vgl = Vt + (size_t)((b * HH + h) * 64 + wq * 16 + srow) * SS + spc;

  // bias: consumer-ordered tiles; per tile 4 coalesced 16B loads/thread into regs
  const _Float16* btile = bias16 + (((size_t)(b * 8 + qt) * 16) << 13) + tid * 8;

  // ---- prologue: stage tile 0 (K/V via gload_lds, bias via regs) ----
  {
    char* kd = (char*)kbuf[0] + wq * 2048;
    char* vd = (char*)vbuf[0] + wq * 2048;
#pragma unroll
    for (int j = 0; j < 2; ++j) {
      __builtin_amdgcn_global_load_lds((gas1_t)(const void*)(kgl + (size_t)(j * 8) * DD),
                                       (las3_t)(void*)(kd + j * 1024), 16, 0, 0);
      __builtin_amdgcn_global_load_lds((gas1_t)(const void*)(vgl + (size_t)(j * 8) * SS),
                                       (las3_t)(void*)(vd + j * 1024), 16, 0, 0);
    }
  }
  f16x8 bbr[4], bbn[4];
#pragma unroll
  for (int g = 0; g < 4; ++g)
    bbr[g] = *(const f16x8*)(btile + g * 2048);
  __syncthreads();

  f32x16 o0 = {}, o1 = {};
  float m = -1e30f, lsum = 0.f;
  int cur = 0;

  for (int kt = 0; kt < 16; ++kt) {
    // 1. stage next tile: K/V -> LDS (async), bias -> regs
    if (kt < 15) {
      char* kd = (char*)kbuf[cur ^ 1] + wq * 2048;
      char* vd = (char*)vbuf[cur ^ 1] + wq * 2048;
      const size_t k1 = (size_t)(kt + 1) * 64;
#pragma unroll
      for (int j = 0; j < 2; ++j) {
        __builtin_amdgcn_global_load_lds((gas1_t)(const void*)(kgl + (k1 + j * 8) * DD),
                                         (las3_t)(void*)(kd + j * 1024), 16, 0, 0);
        __builtin_amdgcn_global_load_lds((gas1_t)(const void*)(vgl + (size_t)(j * 8) * SS + k1),
                                         (las3_t)(void*)(vd + j * 1024), 16, 0, 0);
      }
      const _Float16* bt = btile + ((size_t)(kt + 1) << 13);
#pragma unroll
      for (int g = 0; g < 4; ++g)
        bbn[g] = *(const f16x8*)(bt + g * 2048);
    }

    // 2. swapped QK^T: s = mfma(K, Q) -> C: col = q = ln, row(k) = (r&3)+8*(r>>2)+4*hi (+32*kb)
    const char* kb_base = (const char*)kbuf[cur];
    f32x16 s[2];
#pragma unroll
    for (int kb = 0; kb < 2; ++kb) {
      f32x16 acc = {};
#pragma unroll
      for (int d = 0; d < 4; ++d) {
        bf16x8 kf = *(const bf16x8*)(kb_base + (kb * 32 + ln) * 128 + (((u32)(d * 32 + hi * 16)) ^ swz));
        acc = MFMA32(kf, qf[d], acc);
      }
      s[kb] = acc;
    }

    // 3. scale (D^-0.5 = 1/32) + bias from regs (fragment-ordered fp16)
#pragma unroll
    for (int g = 0; g < 4; ++g) {
      const int kb = g >> 1, rq0 = (g & 1) * 2;
#pragma unroll
      for (int e = 0; e < 8; ++e)
        s[kb][(rq0 + (e >> 2)) * 4 + (e & 3)] =
            fmaf(s[kb][(rq0 + (e >> 2)) * 4 + (e & 3)], 0.03125f, (float)bbr[g][e]);
    }

    // 4. in-register row softmax (row is lane-local; only cross-hi shuffle needed)
    float mt = -1e30f;
#pragma unroll
    for (int r = 0; r < 16; ++r) { mt = fmaxf(mt, s[0][r]); mt = fmaxf(mt, s[1][r]); }
    mt = fmaxf(mt, __shfl_xor(mt, 32));

    bool resc = false;
    float fsc = 1.f;
    if (kt == 0) {
      m = mt;
    } else if (__any(mt > m + 8.f)) {   // T13 defer-max
      float mn = fmaxf(m, mt);
      fsc = __expf(m - mn);
      m = mn;
      resc = true;
    }

    float rs = 0.f;
    u32 wv[2][8];
#pragma unroll
    for (int kb = 0; kb < 2; ++kb)
#pragma unroll
      for (int t = 0; t < 8; ++t) {
        float p0 = __expf(s[kb][2 * t] - m);
        float p1 = __expf(s[kb][2 * t + 1] - m);
        rs += p0 + p1;
        wv[kb][t] = pk2(p0, p1);
      }
    rs += __shfl_xor(rs, 32);
    lsum = lsum * fsc + rs;

    if (resc) {  // rescale O at q' = crow(j,hi), factor fetched via lane broadcast
#pragma unroll
      for (int j = 0; j < 16; ++j) {
        float fv = __shfl(fsc, (j & 3) + 8 * (j >> 2) + 4 * hi);
        o0[j] *= fv; o1[j] *= fv;
      }
    }

    // 5. PV: rebuild P A-fragments in-register (cross-hi shfl), then mfma(P, V)
    const char* vb_base = (const char*)vbuf[cur];
#pragma unroll
    for (int ks = 0; ks < 4; ++ks) {
      const int kb = ks >> 1, i0 = (ks & 1) * 4;
      u32 sA = hi ? wv[kb][i0 + 0] : wv[kb][i0 + 2];
      u32 sB = hi ? wv[kb][i0 + 1] : wv[kb][i0 + 3];
      u32 rA = (u32)__shfl_xor((int)sA, 32);
      u32 rB = (u32)__shfl_xor((int)sB, 32);
      u32 e0 = hi ? rA : wv[kb][i0 + 0];
      u32 e1 = hi ? rB : wv[kb][i0 + 1];
      u32 e2 = hi ? wv[kb][i0 + 2] : rA;
      u32 e3 = hi ? wv[kb][i0 + 3] : rB;
      union { u32x4 u; bf16x8 v; } pc;
      pc.u = (u32x4){e0, e1, e2, e3};
      bf16x8 pa = pc.v;
#pragma unroll
      for (int nv = 0; nv < 2; ++nv) {
        bf16x8 vf = *(const bf16x8*)(vb_base + (nv * 32 + ln) * 128 + (((u32)(ks * 32 + hi * 16)) ^ swz));
        if (nv == 0) o0 = MFMA32(pa, vf, o0);
        else         o1 = MFMA32(pa, vf, o1);
      }
    }

    // 6. single end-of-tile barrier; rotate buffers
    if (kt < 15) {
      __syncthreads();
      cur ^= 1;
#pragma unroll
      for (int g = 0; g < 4; ++g) bbr[g] = bbn[g];
    }
  }

  // epilogue: normalize (1/l broadcast via shfl) + write O (bf16)
  float inv = 1.0f / lsum;
#pragma unroll
  for (int j = 0; j < 16; ++j) {
    float iv = __shfl(inv, (j & 3) + 8 * (j >> 2) + 4 * hi);
    int q = q0 + wq * 32 + (j & 3) + 8 * (j >> 2) + 4 * hi;
    u16* op = O + (size_t)(b * SS + q) * DD + h * 64 + ln;
    op[0]  = f2b(o0[j] * iv);
    op[32] = f2b(o1[j] * iv);
  }
}

// ---------------- host launch ----------------
extern "C" void kernel_launch(void* const* d_in, const int* in_sizes, int n_in,
                              void* d_out, int out_size, void* d_ws, size_t ws_size,
                              hipStream_t stream) {
  const float* queries = (const float*)d_in[0];
  const float* keys    = (const float*)d_in[1];
  const float* values  = (const float*)d_in[2];
  const float* bias    = (const float*)d_in[3];
  const float* Wq      = (const float*)d_in[4];
  const float* Wk      = (const float*)d_in[5];
  const float* Wv      = (const float*)d_in[6];
  const float* Wp      = (const float*)d_in[7];
  float* out = (float*)d_out;

  char* ws = (char*)d_ws;
  const size_t MB = 1024 * 1024;
  u16* qb  = (u16*)(ws + 0 * MB);
  u16* kb  = (u16*)(ws + 8 * MB);
  u16* vb  = (u16*)(ws + 16 * MB);
  u16* wqb = (u16*)(ws + 24 * MB);
  u16* wkb = (u16*)(ws + 26 * MB);
  u16* wvb = (u16*)(ws + 28 * MB);
  u16* wpb = (u16*)(ws + 30 * MB);
  u16* Qb  = (u16*)(ws + 32 * MB);
  u16* Kb  = (u16*)(ws + 40 * MB);
  _Float16* bias16 = (_Float16*)(ws + 48 * MB);  // free region
  u16* Vtb = (u16*)(ws + 56 * MB);
  u16* Ob  = (u16*)(ws + 0 * MB);  // attn output over qb (dead after projections)

  const int nAct = BB * SS * DD;  // 4M
  const int nW = DD * DD;         // 1M

  // conversions + coalesced bias pack in ONE launch
  cvt_all<<<dim3(18432), dim3(256), 0, stream>>>(
      queries, keys, values, Wq, Wk, Wv, Wp, bias,
      qb, kb, vb, wqb, wkb, wvb, wpb, bias16);

  // QKV projections: z=0 -> Qb, z=1 -> Kb, z=2 -> Vt (transposed write)
  gemm_bt<u16, true><<<dim3(8, 32, 3), dim3(256), 0, stream>>>(
      qb, wqb, Qb, Vtb, DD, DD, (size_t)nAct, (size_t)nW, (size_t)nAct);

  attn_kernel<<<dim3(8, 16, 4), dim3(256), 0, stream>>>(Qb, Kb, Vtb, bias16, Ob);

  // output projection: 512-thread blocks, 8 waves (2 waves/SIMD)
  gemm_proj<<<dim3(8, 32), dim3(512), 0, stream>>>(Ob, wpb, out, DD, DD);
}